// Round 4
// baseline (174.687 us; speedup 1.0000x reference)
//
#include <hip/hip_runtime.h>
#include <hip/hip_bf16.h>

// Causal SDPA, B=2 H=16 S=2048 D=64, fp32 in/out, bf16 MFMA compute.
// R8: attack the occupancy cap. R7's double-buffered LDS (36.9 KB/block)
// limited residency to 4 blocks/CU (25% static cap; 12% measured after
// causal drain). Single-buffer K/V (18.4 KB) -> 8 blocks/CU (50% cap) and
// grid(1024) is now 2x under capacity so drained CUs refill. Register
// prefetch keeps global latency hidden under compute; the LDS commit moves
// behind a read-completion barrier (2 barriers/tile, overlapped by 8
// independent blocks/CU). Everything else is R7's verified structure:
// 2 waves x 32 q-rows, 32x32x16 swapped-QK^T, in-register softmax with
// pre-permuted V (no lane exchange), ones-MFMA rowsum.

#define BHN 32
#define SEQ 2048
#define DIM 64
#define LSTR 72  // LDS row stride (bf16): 144 B, conflict-free (measured 0)

typedef __attribute__((ext_vector_type(8)))  short    short8;
typedef __attribute__((ext_vector_type(4)))  short    short4v;
typedef __attribute__((ext_vector_type(4)))  float    float4v;
typedef __attribute__((ext_vector_type(16))) float    f32x16;
typedef __attribute__((ext_vector_type(4)))  unsigned uint4v;

__device__ __forceinline__ short f2b(float x) {
  __hip_bfloat16 h = __float2bfloat16(x);
  return __builtin_bit_cast(short, h);
}

// ---- pre-pass: K fp32->bf16 (same layout) + V fp32->bf16 transposed,
//      with per-16-k-group column permutation [0..3, 8..11, 4..7, 12..15].
__global__ __launch_bounds__(256) void prep_kernel(
    const float* __restrict__ K, const float* __restrict__ V,
    __hip_bfloat16* __restrict__ Kb, __hip_bfloat16* __restrict__ Vt) {
  __shared__ float t[64][65];
  const int bh = blockIdx.x, j = blockIdx.y, tid = threadIdx.x;
  const int r = tid >> 2, seg = (tid & 3) * 16;
  const size_t base = (size_t)bh * SEQ * DIM;
  {
    const float* ks = K + base + (size_t)(j * 64 + r) * DIM + seg;
    float4v k0 = *(const float4v*)(ks + 0);
    float4v k1 = *(const float4v*)(ks + 4);
    float4v k2 = *(const float4v*)(ks + 8);
    float4v k3 = *(const float4v*)(ks + 12);
    short8 a, b;
    a[0]=f2b(k0[0]); a[1]=f2b(k0[1]); a[2]=f2b(k0[2]); a[3]=f2b(k0[3]);
    a[4]=f2b(k1[0]); a[5]=f2b(k1[1]); a[6]=f2b(k1[2]); a[7]=f2b(k1[3]);
    b[0]=f2b(k2[0]); b[1]=f2b(k2[1]); b[2]=f2b(k2[2]); b[3]=f2b(k2[3]);
    b[4]=f2b(k3[0]); b[5]=f2b(k3[1]); b[6]=f2b(k3[2]); b[7]=f2b(k3[3]);
    __hip_bfloat16* kd = Kb + base + (size_t)(j * 64 + r) * DIM + seg;
    *(short8*)kd = a;
    *(short8*)(kd + 8) = b;
  }
  {
    const float* src = V + base + (size_t)(j * 64 + r) * DIM + seg;
    float4v f0 = *(const float4v*)(src + 0);
    float4v f1 = *(const float4v*)(src + 4);
    float4v f2 = *(const float4v*)(src + 8);
    float4v f3 = *(const float4v*)(src + 12);
    *(float4v*)&t[r][seg + 0]  = f0;
    *(float4v*)&t[r][seg + 4]  = f1;
    *(float4v*)&t[r][seg + 8]  = f2;
    *(float4v*)&t[r][seg + 12] = f3;
    __syncthreads();
    // stored order within this 16-k group: [0,1,2,3, 8,9,10,11, 4,5,6,7, 12,13,14,15]
    short8 n0, n1;
    #pragma unroll
    for (int i = 0; i < 4; ++i) {
      n0[i]     = f2b(t[seg + i][r]);        // k = 0..3
      n0[4 + i] = f2b(t[seg + 8 + i][r]);    // k = 8..11
      n1[i]     = f2b(t[seg + 4 + i][r]);    // k = 4..7
      n1[4 + i] = f2b(t[seg + 12 + i][r]);   // k = 12..15
    }
    __hip_bfloat16* dst = Vt + (size_t)bh * DIM * SEQ + (size_t)r * SEQ + j * 64 + seg;
    *(short8*)dst = n0;
    *(short8*)(dst + 8) = n1;
  }
}

// ---------------------------- main flash kernel ---------------------------
// 2 waves x 32 q-rows (64 rows/block), 32x32x16 MFMA, swapped QK^T,
// in-register softmax, ones-MFMA rowsum, pre-permuted V, single-buffer LDS.
__global__ __launch_bounds__(128, 4) void fattn8(
    const float* __restrict__ Qg, const __hip_bfloat16* __restrict__ Kb,
    const __hip_bfloat16* __restrict__ Vt, float* __restrict__ Og) {
  __shared__ alignas(16) __hip_bfloat16 kt[64][LSTR];
  __shared__ alignas(16) __hip_bfloat16 vt[64][LSTR];

  const int bh   = blockIdx.x;
  const int qt   = gridDim.y - 1 - blockIdx.y;  // longest blocks first
  const int tid  = threadIdx.x;
  const int w    = tid >> 6;
  const int lane = tid & 63;
  const int l31  = lane & 31;
  const int hi   = lane >> 5;
  const size_t base  = (size_t)bh * SEQ * DIM;
  const size_t baseV = (size_t)bh * DIM * SEQ;
  const int q0   = qt * 64;

  const float QSCALE = 0.125f * 1.44269504088896340736f;  // scale * log2(e)

  // Q fragments (B-operand of swapped QK^T): qf[s][i] = Q[q0+32w+l31][16s+8hi+i]
  short8 qf[4];
  {
    const float* qp = Qg + base + (size_t)(q0 + 32 * w + l31) * DIM + 8 * hi;
    #pragma unroll
    for (int s = 0; s < 4; ++s) {
      float4v f0 = *(const float4v*)(qp + 16 * s);
      float4v f1 = *(const float4v*)(qp + 16 * s + 4);
      short8 qv;
      qv[0] = f2b(f0[0] * QSCALE); qv[1] = f2b(f0[1] * QSCALE);
      qv[2] = f2b(f0[2] * QSCALE); qv[3] = f2b(f0[3] * QSCALE);
      qv[4] = f2b(f1[0] * QSCALE); qv[5] = f2b(f1[1] * QSCALE);
      qv[6] = f2b(f1[2] * QSCALE); qv[7] = f2b(f1[3] * QSCALE);
      qf[s] = qv;
    }
  }

  short8 ones;
  #pragma unroll
  for (int x = 0; x < 8; ++x) ones[x] = (short)0x3F80;  // bf16 1.0

  f32x16 o0, o1, l16;
  #pragma unroll
  for (int i = 0; i < 16; ++i) { o0[i] = 0.f; o1[i] = 0.f; l16[i] = 0.f; }

  // staging: 128 threads cover 64 rows x 64 cols (32 cols/thread)
  const int srow = tid >> 1;          // 0..63
  const int scol = (tid & 1) * 32;    // 0 or 32

  short8 sk[4], sv[4];
  {
    const __hip_bfloat16* kp = Kb + base + (size_t)srow * DIM + scol;
    const __hip_bfloat16* vp = Vt + baseV + (size_t)srow * SEQ + scol;
    #pragma unroll
    for (int i = 0; i < 4; ++i) { sk[i] = *(const short8*)(kp + 8 * i); }
    #pragma unroll
    for (int i = 0; i < 4; ++i) { sv[i] = *(const short8*)(vp + 8 * i); }
  }
  #pragma unroll
  for (int i = 0; i < 4; ++i) {
    *(short8*)&kt[srow][scol + 8 * i] = sk[i];
    *(short8*)&vt[srow][scol + 8 * i] = sv[i];
  }
  __syncthreads();

  for (int j = 0; j <= qt; ++j) {
    // issue global loads for tile j+1 early (hidden under QK^T + softmax + PV)
    if (j < qt) {
      const int kb = (j + 1) * 64;
      const __hip_bfloat16* kp = Kb + base + (size_t)(kb + srow) * DIM + scol;
      const __hip_bfloat16* vp = Vt + baseV + (size_t)srow * SEQ + kb + scol;
      #pragma unroll
      for (int i = 0; i < 4; ++i) { sk[i] = *(const short8*)(kp + 8 * i); }
      #pragma unroll
      for (int i = 0; i < 4; ++i) { sv[i] = *(const short8*)(vp + 8 * i); }
    }

    // ---- S^T = K · Q^T  (D: col=lane&31=q, rows over regs = k_rel)
    f32x16 p0, p1;
    #pragma unroll
    for (int i = 0; i < 16; ++i) { p0[i] = 0.f; p1[i] = 0.f; }
    __builtin_amdgcn_s_setprio(1);
    #pragma unroll
    for (int s = 0; s < 4; ++s) {
      short8 a0 = *(const short8*)&kt[l31][16 * s + 8 * hi];
      short8 a1 = *(const short8*)&kt[32 + l31][16 * s + 8 * hi];
      p0 = __builtin_amdgcn_mfma_f32_32x32x16_bf16(a0, qf[s], p0, 0, 0, 0);
      p1 = __builtin_amdgcn_mfma_f32_32x32x16_bf16(a1, qf[s], p1, 0, 0, 0);
    }
    __builtin_amdgcn_s_setprio(0);

    // ---- causal mask (diagonal tile only)
    if (j == qt) {
      const int qg  = q0 + 32 * w + l31;
      const int kb0 = 64 * j + 4 * hi;
      #pragma unroll
      for (int r = 0; r < 16; ++r) {
        const int kr = kb0 + (r & 3) + 8 * (r >> 2);
        if (kr > qg)      p0[r] = -1e30f;
        if (kr + 32 > qg) p1[r] = -1e30f;
      }
    }

    // ---- P = exp2(S), pack to bf16 in-register (natural order; V was
    //      pre-permuted to match, so pw IS the PV A-fragment)
    #pragma unroll
    for (int i = 0; i < 16; ++i) {
      p0[i] = __builtin_amdgcn_exp2f(p0[i]);
      p1[i] = __builtin_amdgcn_exp2f(p1[i]);
    }
    unsigned pw[16];
    #pragma unroll
    for (int i = 0; i < 8; ++i)
      asm("v_cvt_pk_bf16_f32 %0, %1, %2"
          : "=v"(pw[i]) : "v"(p0[2 * i]), "v"(p0[2 * i + 1]));
    #pragma unroll
    for (int i = 0; i < 8; ++i)
      asm("v_cvt_pk_bf16_f32 %0, %1, %2"
          : "=v"(pw[8 + i]) : "v"(p1[2 * i]), "v"(p1[2 * i + 1]));

    // ---- O += P V, l += P·1 (rowsum on MFMA pipe, reg-indexed like o)
    __builtin_amdgcn_s_setprio(1);
    #pragma unroll
    for (int t = 0; t < 4; ++t) {
      uint4v u = {pw[4 * t], pw[4 * t + 1], pw[4 * t + 2], pw[4 * t + 3]};
      short8 pa = __builtin_bit_cast(short8, u);
      short8 b0 = *(const short8*)&vt[l31][16 * t + 8 * hi];
      short8 b1 = *(const short8*)&vt[32 + l31][16 * t + 8 * hi];
      o0  = __builtin_amdgcn_mfma_f32_32x32x16_bf16(pa, b0, o0, 0, 0, 0);
      o1  = __builtin_amdgcn_mfma_f32_32x32x16_bf16(pa, b1, o1, 0, 0, 0);
      l16 = __builtin_amdgcn_mfma_f32_32x32x16_bf16(pa, ones, l16, 0, 0, 0);
    }
    __builtin_amdgcn_s_setprio(0);

    // ---- commit tile j+1 into the single LDS buffer
    if (j < qt) {
      __syncthreads();  // all reads of tile j complete
      #pragma unroll
      for (int i = 0; i < 4; ++i) {
        *(short8*)&kt[srow][scol + 8 * i] = sk[i];
        *(short8*)&vt[srow][scol + 8 * i] = sv[i];
      }
      __syncthreads();  // tile j+1 visible
    }
  }

  // ---- epilogue: O /= l   (l16[r] holds rowsum of the same q-row as o[r])
  float* op = Og + base + (size_t)(q0 + 32 * w) * DIM + l31;
  #pragma unroll
  for (int r = 0; r < 16; ++r) {
    const int row = (r & 3) + 8 * (r >> 2) + 4 * hi;
    const float iv = 1.0f / l16[r];
    op[(size_t)row * DIM]      = o0[r] * iv;
    op[(size_t)row * DIM + 32] = o1[r] * iv;
  }
}

// --------------- fallback if ws too small: in-kernel cast -----------------
__global__ __launch_bounds__(256) void fattn_ref(
    const float* __restrict__ Qg, const float* __restrict__ Kg,
    const float* __restrict__ Vg, float* __restrict__ Og) {
  __shared__ alignas(16) __hip_bfloat16 kt[64][LSTR];
  __shared__ alignas(16) __hip_bfloat16 vt[64][LSTR];
  __shared__ alignas(16) __hip_bfloat16 pt[4][16][LSTR];

  const int bh   = blockIdx.x;
  const int qt   = gridDim.y - 1 - blockIdx.y;
  const int tid  = threadIdx.x;
  const int wave = tid >> 6;
  const int lane = tid & 63;
  const int ln   = lane & 15;
  const int quad = lane >> 4;
  const size_t base = (size_t)bh * SEQ * DIM;
  const int q0 = qt * 64;

  const float QSCALE = 0.125f * 1.44269504088896340736f;
  short8 qf[2];
  {
    const int qrow = q0 + wave * 16 + ln;
    const float* qp = Qg + base + (size_t)qrow * DIM + quad * 8;
    #pragma unroll
    for (int kk = 0; kk < 2; ++kk) {
      float4v f0 = *(const float4v*)(qp + kk * 32);
      float4v f1 = *(const float4v*)(qp + kk * 32 + 4);
      short8 qv;
      qv[0] = f2b(f0[0] * QSCALE); qv[1] = f2b(f0[1] * QSCALE);
      qv[2] = f2b(f0[2] * QSCALE); qv[3] = f2b(f0[3] * QSCALE);
      qv[4] = f2b(f1[0] * QSCALE); qv[5] = f2b(f1[1] * QSCALE);
      qv[6] = f2b(f1[2] * QSCALE); qv[7] = f2b(f1[3] * QSCALE);
      qf[kk] = qv;
    }
  }
  float4v o[4];
  #pragma unroll
  for (int dt = 0; dt < 4; ++dt) { float4v z = {0.f,0.f,0.f,0.f}; o[dt] = z; }
  float l_i[4] = {0.f, 0.f, 0.f, 0.f};

  for (int j = 0; j <= qt; ++j) {
    const int kbase = j * 64;
    __syncthreads();
    {
      const int r = tid >> 4, c = (tid & 15) * 4;
      #pragma unroll
      for (int it = 0; it < 4; ++it) {
        const int row = it * 16 + r;
        float4v f = *(const float4v*)(Kg + base + (size_t)(kbase + row) * DIM + c);
        short4v sv; sv[0]=f2b(f[0]); sv[1]=f2b(f[1]); sv[2]=f2b(f[2]); sv[3]=f2b(f[3]);
        *(short4v*)&kt[row][c] = sv;
      }
      const int d = tid & 63, s0 = (tid >> 6) * 4;
      #pragma unroll
      for (int it = 0; it < 4; ++it) {
        const int sk = it * 16 + s0;
        short4v sv;
        sv[0] = f2b(Vg[base + (size_t)(kbase + sk + 0) * DIM + d]);
        sv[1] = f2b(Vg[base + (size_t)(kbase + sk + 1) * DIM + d]);
        sv[2] = f2b(Vg[base + (size_t)(kbase + sk + 2) * DIM + d]);
        sv[3] = f2b(Vg[base + (size_t)(kbase + sk + 3) * DIM + d]);
        *(short4v*)&vt[d][sk] = sv;
      }
    }
    __syncthreads();

    float4v s[4];
    #pragma unroll
    for (int nt = 0; nt < 4; ++nt) {
      short8 b0 = *(const short8*)&kt[nt * 16 + ln][quad * 8];
      short8 b1 = *(const short8*)&kt[nt * 16 + ln][32 + quad * 8];
      float4v acc = {0.f,0.f,0.f,0.f};
      acc = __builtin_amdgcn_mfma_f32_16x16x32_bf16(qf[0], b0, acc, 0, 0, 0);
      acc = __builtin_amdgcn_mfma_f32_16x16x32_bf16(qf[1], b1, acc, 0, 0, 0);
      s[nt] = acc;
    }
    if (j == qt) {
      #pragma unroll
      for (int nt = 0; nt < 4; ++nt) {
        const int col = nt * 16 + ln;
        #pragma unroll
        for (int rg = 0; rg < 4; ++rg)
          if (col > wave * 16 + quad * 4 + rg) s[nt][rg] = -1e30f;
      }
    }
    #pragma unroll
    for (int rg = 0; rg < 4; ++rg) {
      float p0 = __builtin_amdgcn_exp2f(s[0][rg]);
      float p1 = __builtin_amdgcn_exp2f(s[1][rg]);
      float p2 = __builtin_amdgcn_exp2f(s[2][rg]);
      float p3 = __builtin_amdgcn_exp2f(s[3][rg]);
      s[0][rg]=p0; s[1][rg]=p1; s[2][rg]=p2; s[3][rg]=p3;
      float rs = (p0 + p1) + (p2 + p3);
      rs += __shfl_xor(rs, 1, 64); rs += __shfl_xor(rs, 2, 64);
      rs += __shfl_xor(rs, 4, 64); rs += __shfl_xor(rs, 8, 64);
      l_i[rg] += rs;
    }
    #pragma unroll
    for (int nt = 0; nt < 4; ++nt)
      #pragma unroll
      for (int rg = 0; rg < 4; ++rg)
        pt[wave][quad * 4 + rg][nt * 16 + ln] = __float2bfloat16(s[nt][rg]);
    short8 pa0 = *(const short8*)&pt[wave][ln][quad * 8];
    short8 pa1 = *(const short8*)&pt[wave][ln][32 + quad * 8];
    #pragma unroll
    for (int dt = 0; dt < 4; ++dt) {
      short8 vb0 = *(const short8*)&vt[dt * 16 + ln][quad * 8];
      short8 vb1 = *(const short8*)&vt[dt * 16 + ln][32 + quad * 8];
      o[dt] = __builtin_amdgcn_mfma_f32_16x16x32_bf16(pa0, vb0, o[dt], 0, 0, 0);
      o[dt] = __builtin_amdgcn_mfma_f32_16x16x32_bf16(pa1, vb1, o[dt], 0, 0, 0);
    }
  }
  #pragma unroll
  for (int rg = 0; rg < 4; ++rg) {
    const float inv = 1.0f / l_i[rg];
    const int row = q0 + wave * 16 + quad * 4 + rg;
    float* op = Og + base + (size_t)row * DIM + ln;
    #pragma unroll
    for (int dt = 0; dt < 4; ++dt) op[dt * 16] = o[dt][rg] * inv;
  }
}

extern "C" void kernel_launch(void* const* d_in, const int* in_sizes, int n_in,
                              void* d_out, int out_size, void* d_ws, size_t ws_size,
                              hipStream_t stream) {
  (void)in_sizes; (void)n_in; (void)out_size;
  const float* Q = (const float*)d_in[0];
  const float* K = (const float*)d_in[1];
  const float* V = (const float*)d_in[2];
  float* O = (float*)d_out;
  const size_t need = (size_t)2 * BHN * SEQ * DIM * sizeof(__hip_bfloat16); // 16 MB
  if (ws_size >= need) {
    __hip_bfloat16* Kb = (__hip_bfloat16*)d_ws;
    __hip_bfloat16* Vt = Kb + (size_t)BHN * SEQ * DIM;
    prep_kernel<<<dim3(BHN, SEQ / 64), 256, 0, stream>>>(K, V, Kb, Vt);
    fattn8<<<dim3(BHN, SEQ / 64), 128, 0, stream>>>(Q, Kb, Vt, O);
  } else {
    fattn_ref<<<dim3(BHN, SEQ / 64), 256, 0, stream>>>(Q, K, V, O);
  }
}

// Round 7
// 150.571 us; speedup vs baseline: 1.1602x; 1.1602x over previous
//
#include <hip/hip_runtime.h>
#include <hip/hip_bf16.h>

// Causal SDPA, B=2 H=16 S=2048 D=64, fp32 in/out, bf16 MFMA compute.
// R11: back to the VERIFIED R7 math (LDS-staged K/Vt, swapped 32x32x16 QK^T,
// in-register softmax, pre-permuted V so pw[] is directly the PV A-fragment,
// ones-MFMA rowsum). R9/R10's packed-global path failed un-localizably and
// is abandoned. New here, attacking R7's measured 52% causal duty factor:
//  - wave w of block b owns q-tile (w ? 63-b : b) of 32 rows -> every block
//    runs exactly 33 k-tile iterations (perfect static balance, no drain).
//  - LDS is per-wave PRIVATE (kt[w]/vt[w]) -> NO __syncthreads anywhere;
//    wave-internal lgkmcnt ordering is enough.
//  - staging: K loads issued at iter top, committed after QK; V loads
//    issued after, committed after PV (latency hidden under compute).

#define BHN 32
#define SEQ 2048
#define DIM 64
#define LSTR 72  // LDS row stride (bf16): 144 B, conflict-free (measured 0)

typedef __attribute__((ext_vector_type(8)))  short    short8;
typedef __attribute__((ext_vector_type(4)))  short    short4v;
typedef __attribute__((ext_vector_type(4)))  float    float4v;
typedef __attribute__((ext_vector_type(16))) float    f32x16;
typedef __attribute__((ext_vector_type(4)))  unsigned uint4v;

__device__ __forceinline__ short f2b(float x) {
  __hip_bfloat16 h = __float2bfloat16(x);
  return __builtin_bit_cast(short, h);
}

// ---- pre-pass (VERIFIED R7): K fp32->bf16 (same layout) + V fp32->bf16
//      transposed, k-columns permuted per 16-group [0..3,8..11,4..7,12..15].
__global__ __launch_bounds__(256) void prep_kernel(
    const float* __restrict__ K, const float* __restrict__ V,
    __hip_bfloat16* __restrict__ Kb, __hip_bfloat16* __restrict__ Vt) {
  __shared__ float t[64][65];
  const int bh = blockIdx.x, j = blockIdx.y, tid = threadIdx.x;
  const int r = tid >> 2, seg = (tid & 3) * 16;
  const size_t base = (size_t)bh * SEQ * DIM;
  {
    const float* ks = K + base + (size_t)(j * 64 + r) * DIM + seg;
    float4v k0 = *(const float4v*)(ks + 0);
    float4v k1 = *(const float4v*)(ks + 4);
    float4v k2 = *(const float4v*)(ks + 8);
    float4v k3 = *(const float4v*)(ks + 12);
    short8 a, b;
    a[0]=f2b(k0[0]); a[1]=f2b(k0[1]); a[2]=f2b(k0[2]); a[3]=f2b(k0[3]);
    a[4]=f2b(k1[0]); a[5]=f2b(k1[1]); a[6]=f2b(k1[2]); a[7]=f2b(k1[3]);
    b[0]=f2b(k2[0]); b[1]=f2b(k2[1]); b[2]=f2b(k2[2]); b[3]=f2b(k2[3]);
    b[4]=f2b(k3[0]); b[5]=f2b(k3[1]); b[6]=f2b(k3[2]); b[7]=f2b(k3[3]);
    __hip_bfloat16* kd = Kb + base + (size_t)(j * 64 + r) * DIM + seg;
    *(short8*)kd = a;
    *(short8*)(kd + 8) = b;
  }
  {
    const float* src = V + base + (size_t)(j * 64 + r) * DIM + seg;
    float4v f0 = *(const float4v*)(src + 0);
    float4v f1 = *(const float4v*)(src + 4);
    float4v f2 = *(const float4v*)(src + 8);
    float4v f3 = *(const float4v*)(src + 12);
    *(float4v*)&t[r][seg + 0]  = f0;
    *(float4v*)&t[r][seg + 4]  = f1;
    *(float4v*)&t[r][seg + 8]  = f2;
    *(float4v*)&t[r][seg + 12] = f3;
    __syncthreads();
    // stored order within 16-k group: [0,1,2,3, 8,9,10,11, 4,5,6,7, 12,13,14,15]
    short8 n0, n1;
    #pragma unroll
    for (int i = 0; i < 4; ++i) {
      n0[i]     = f2b(t[seg + i][r]);        // k = 0..3
      n0[4 + i] = f2b(t[seg + 8 + i][r]);    // k = 8..11
      n1[i]     = f2b(t[seg + 4 + i][r]);    // k = 4..7
      n1[4 + i] = f2b(t[seg + 12 + i][r]);   // k = 12..15
    }
    __hip_bfloat16* dst = Vt + (size_t)bh * DIM * SEQ + (size_t)r * SEQ + j * 64 + seg;
    *(short8*)dst = n0;
    *(short8*)(dst + 8) = n1;
  }
}

// ---------------------------- main flash kernel ---------------------------
// 2 waves/block, wave w owns q-tile (w ? 63-b : b) of 32 rows; per-wave
// private LDS; no barriers; 33 iterations per block (perfectly balanced).
__global__ __launch_bounds__(128) void fattn11(
    const float* __restrict__ Qg, const __hip_bfloat16* __restrict__ Kb,
    const __hip_bfloat16* __restrict__ Vt, float* __restrict__ Og) {
  __shared__ alignas(16) __hip_bfloat16 kt[2][64][LSTR];
  __shared__ alignas(16) __hip_bfloat16 vt[2][64][LSTR];

  const int bh   = blockIdx.x;
  const int b    = blockIdx.y;
  const int tid  = threadIdx.x;
  const int w    = tid >> 6;
  const int lane = tid & 63;
  const int l31  = lane & 31;
  const int hi   = lane >> 5;
  const int qt2  = w ? (63 - b) : b;    // 32-row q-tile index, 0..63
  const int q0   = qt2 * 32;
  const int jend = qt2 >> 1;            // last k-tile (diagonal)
  const size_t base  = (size_t)bh * SEQ * DIM;
  const size_t baseV = (size_t)bh * DIM * SEQ;

  const float QSCALE = 0.125f * 1.44269504088896340736f;  // scale * log2(e)

  // Q fragments (B-operand of swapped QK^T): qf[s][i] = Q[q0+l31][16s+8hi+i]
  short8 qf[4];
  {
    const float* qp = Qg + base + (size_t)(q0 + l31) * DIM + 8 * hi;
    #pragma unroll
    for (int s = 0; s < 4; ++s) {
      float4v f0 = *(const float4v*)(qp + 16 * s);
      float4v f1 = *(const float4v*)(qp + 16 * s + 4);
      short8 qv;
      qv[0] = f2b(f0[0] * QSCALE); qv[1] = f2b(f0[1] * QSCALE);
      qv[2] = f2b(f0[2] * QSCALE); qv[3] = f2b(f0[3] * QSCALE);
      qv[4] = f2b(f1[0] * QSCALE); qv[5] = f2b(f1[1] * QSCALE);
      qv[6] = f2b(f1[2] * QSCALE); qv[7] = f2b(f1[3] * QSCALE);
      qf[s] = qv;
    }
  }

  short8 ones;
  #pragma unroll
  for (int x = 0; x < 8; ++x) ones[x] = (short)0x3F80;  // bf16 1.0

  f32x16 o0, o1, l16;
  #pragma unroll
  for (int i = 0; i < 16; ++i) { o0[i] = 0.f; o1[i] = 0.f; l16[i] = 0.f; }

  // per-wave staging: lane covers rows lr2 and lr2+32, cols ch..ch+31
  const int lr2 = lane >> 1;          // 0..31
  const int ch  = (lane & 1) * 32;    // 0 or 32

  short8 sk[8], sv[8];

  // prologue: tile 0 -> regs -> private LDS
  {
    const __hip_bfloat16* kp0 = Kb + base + (size_t)lr2 * DIM + ch;
    const __hip_bfloat16* kp1 = Kb + base + (size_t)(lr2 + 32) * DIM + ch;
    const __hip_bfloat16* vp0 = Vt + baseV + (size_t)lr2 * SEQ + ch;
    const __hip_bfloat16* vp1 = Vt + baseV + (size_t)(lr2 + 32) * SEQ + ch;
    #pragma unroll
    for (int i = 0; i < 4; ++i) {
      sk[i]     = *(const short8*)(kp0 + 8 * i);
      sk[4 + i] = *(const short8*)(kp1 + 8 * i);
      sv[i]     = *(const short8*)(vp0 + 8 * i);
      sv[4 + i] = *(const short8*)(vp1 + 8 * i);
    }
  }
  #pragma unroll
  for (int i = 0; i < 4; ++i) {
    *(short8*)&kt[w][lr2][ch + 8 * i]      = sk[i];
    *(short8*)&kt[w][lr2 + 32][ch + 8 * i] = sk[4 + i];
    *(short8*)&vt[w][lr2][ch + 8 * i]      = sv[i];
    *(short8*)&vt[w][lr2 + 32][ch + 8 * i] = sv[4 + i];
  }

  for (int j = 0; j <= jend; ++j) {
    // issue K loads for tile j+1 (committed after QK; latency under softmax)
    if (j < jend) {
      const int kb = (j + 1) * 64;
      const __hip_bfloat16* kp0 = Kb + base + (size_t)(kb + lr2) * DIM + ch;
      const __hip_bfloat16* kp1 = Kb + base + (size_t)(kb + lr2 + 32) * DIM + ch;
      #pragma unroll
      for (int i = 0; i < 4; ++i) {
        sk[i]     = *(const short8*)(kp0 + 8 * i);
        sk[4 + i] = *(const short8*)(kp1 + 8 * i);
      }
    }

    // ---- S^T = K · Q^T  (D: col=l31=q, rows over regs = k_rel)
    f32x16 p0, p1;
    #pragma unroll
    for (int i = 0; i < 16; ++i) { p0[i] = 0.f; p1[i] = 0.f; }
    __builtin_amdgcn_s_setprio(1);
    #pragma unroll
    for (int s = 0; s < 4; ++s) {
      short8 a0 = *(const short8*)&kt[w][l31][16 * s + 8 * hi];
      short8 a1 = *(const short8*)&kt[w][32 + l31][16 * s + 8 * hi];
      p0 = __builtin_amdgcn_mfma_f32_32x32x16_bf16(a0, qf[s], p0, 0, 0, 0);
      p1 = __builtin_amdgcn_mfma_f32_32x32x16_bf16(a1, qf[s], p1, 0, 0, 0);
    }
    __builtin_amdgcn_s_setprio(0);

    // ---- causal mask (diagonal tile only)
    if (j == jend) {
      const int qg  = q0 + l31;
      const int kb0 = 64 * j + 4 * hi;
      #pragma unroll
      for (int r = 0; r < 16; ++r) {
        const int kr = kb0 + (r & 3) + 8 * (r >> 2);
        if (kr > qg)      p0[r] = -1e30f;
        if (kr + 32 > qg) p1[r] = -1e30f;
      }
    }

    // ---- P = exp2(S), pack to bf16 (V pre-permuted: pw IS the A-fragment)
    #pragma unroll
    for (int i = 0; i < 16; ++i) {
      p0[i] = __builtin_amdgcn_exp2f(p0[i]);
      p1[i] = __builtin_amdgcn_exp2f(p1[i]);
    }
    unsigned pw[16];
    #pragma unroll
    for (int i = 0; i < 8; ++i)
      asm("v_cvt_pk_bf16_f32 %0, %1, %2"
          : "=v"(pw[i]) : "v"(p0[2 * i]), "v"(p0[2 * i + 1]));
    #pragma unroll
    for (int i = 0; i < 8; ++i)
      asm("v_cvt_pk_bf16_f32 %0, %1, %2"
          : "=v"(pw[8 + i]) : "v"(p1[2 * i]), "v"(p1[2 * i + 1]));

    // commit K tile j+1 (QK reads of kt done); issue V loads for tile j+1
    if (j < jend) {
      #pragma unroll
      for (int i = 0; i < 4; ++i) {
        *(short8*)&kt[w][lr2][ch + 8 * i]      = sk[i];
        *(short8*)&kt[w][lr2 + 32][ch + 8 * i] = sk[4 + i];
      }
      const int kb = (j + 1) * 64;
      const __hip_bfloat16* vp0 = Vt + baseV + (size_t)lr2 * SEQ + kb + ch;
      const __hip_bfloat16* vp1 = Vt + baseV + (size_t)(lr2 + 32) * SEQ + kb + ch;
      #pragma unroll
      for (int i = 0; i < 4; ++i) {
        sv[i]     = *(const short8*)(vp0 + 8 * i);
        sv[4 + i] = *(const short8*)(vp1 + 8 * i);
      }
    }

    // ---- O += P V, l += P·1 (rowsum on MFMA pipe, reg-indexed like o)
    __builtin_amdgcn_s_setprio(1);
    #pragma unroll
    for (int t = 0; t < 4; ++t) {
      uint4v u = {pw[4 * t], pw[4 * t + 1], pw[4 * t + 2], pw[4 * t + 3]};
      short8 pa = __builtin_bit_cast(short8, u);
      short8 b0 = *(const short8*)&vt[w][l31][16 * t + 8 * hi];
      short8 b1 = *(const short8*)&vt[w][32 + l31][16 * t + 8 * hi];
      o0  = __builtin_amdgcn_mfma_f32_32x32x16_bf16(pa, b0, o0, 0, 0, 0);
      o1  = __builtin_amdgcn_mfma_f32_32x32x16_bf16(pa, b1, o1, 0, 0, 0);
      l16 = __builtin_amdgcn_mfma_f32_32x32x16_bf16(pa, ones, l16, 0, 0, 0);
    }
    __builtin_amdgcn_s_setprio(0);

    // commit V tile j+1 (PV reads of vt done; slack = next QK+softmax)
    if (j < jend) {
      #pragma unroll
      for (int i = 0; i < 4; ++i) {
        *(short8*)&vt[w][lr2][ch + 8 * i]      = sv[i];
        *(short8*)&vt[w][lr2 + 32][ch + 8 * i] = sv[4 + i];
      }
    }
  }

  // ---- epilogue: O /= l   (l16[r] holds rowsum of the same q-row as o[r])
  float* op = Og + base + (size_t)q0 * DIM + l31;
  #pragma unroll
  for (int r = 0; r < 16; ++r) {
    const int row = (r & 3) + 8 * (r >> 2) + 4 * hi;
    const float iv = 1.0f / l16[r];
    op[(size_t)row * DIM]      = o0[r] * iv;
    op[(size_t)row * DIM + 32] = o1[r] * iv;
  }
}

// --------------- fallback if ws too small: in-kernel cast -----------------
__global__ __launch_bounds__(256) void fattn_ref(
    const float* __restrict__ Qg, const float* __restrict__ Kg,
    const float* __restrict__ Vg, float* __restrict__ Og) {
  __shared__ alignas(16) __hip_bfloat16 kt[64][LSTR];
  __shared__ alignas(16) __hip_bfloat16 vt[64][LSTR];
  __shared__ alignas(16) __hip_bfloat16 pt[4][16][LSTR];

  const int bh   = blockIdx.x;
  const int qt   = gridDim.y - 1 - blockIdx.y;
  const int tid  = threadIdx.x;
  const int wave = tid >> 6;
  const int lane = tid & 63;
  const int ln   = lane & 15;
  const int quad = lane >> 4;
  const size_t base = (size_t)bh * SEQ * DIM;
  const int q0 = qt * 64;

  const float QSCALE = 0.125f * 1.44269504088896340736f;
  short8 qf[2];
  {
    const int qrow = q0 + wave * 16 + ln;
    const float* qp = Qg + base + (size_t)qrow * DIM + quad * 8;
    #pragma unroll
    for (int kk = 0; kk < 2; ++kk) {
      float4v f0 = *(const float4v*)(qp + kk * 32);
      float4v f1 = *(const float4v*)(qp + kk * 32 + 4);
      short8 qv;
      qv[0] = f2b(f0[0] * QSCALE); qv[1] = f2b(f0[1] * QSCALE);
      qv[2] = f2b(f0[2] * QSCALE); qv[3] = f2b(f0[3] * QSCALE);
      qv[4] = f2b(f1[0] * QSCALE); qv[5] = f2b(f1[1] * QSCALE);
      qv[6] = f2b(f1[2] * QSCALE); qv[7] = f2b(f1[3] * QSCALE);
      qf[kk] = qv;
    }
  }
  float4v o[4];
  #pragma unroll
  for (int dt = 0; dt < 4; ++dt) { float4v z = {0.f,0.f,0.f,0.f}; o[dt] = z; }
  float l_i[4] = {0.f, 0.f, 0.f, 0.f};

  for (int j = 0; j <= qt; ++j) {
    const int kbase = j * 64;
    __syncthreads();
    {
      const int r = tid >> 4, c = (tid & 15) * 4;
      #pragma unroll
      for (int it = 0; it < 4; ++it) {
        const int row = it * 16 + r;
        float4v f = *(const float4v*)(Kg + base + (size_t)(kbase + row) * DIM + c);
        short4v sv; sv[0]=f2b(f[0]); sv[1]=f2b(f[1]); sv[2]=f2b(f[2]); sv[3]=f2b(f[3]);
        *(short4v*)&kt[row][c] = sv;
      }
      const int d = tid & 63, s0 = (tid >> 6) * 4;
      #pragma unroll
      for (int it = 0; it < 4; ++it) {
        const int sk = it * 16 + s0;
        short4v sv;
        sv[0] = f2b(Vg[base + (size_t)(kbase + sk + 0) * DIM + d]);
        sv[1] = f2b(Vg[base + (size_t)(kbase + sk + 1) * DIM + d]);
        sv[2] = f2b(Vg[base + (size_t)(kbase + sk + 2) * DIM + d]);
        sv[3] = f2b(Vg[base + (size_t)(kbase + sk + 3) * DIM + d]);
        *(short4v*)&vt[d][sk] = sv;
      }
    }
    __syncthreads();

    float4v s[4];
    #pragma unroll
    for (int nt = 0; nt < 4; ++nt) {
      short8 b0 = *(const short8*)&kt[nt * 16 + ln][quad * 8];
      short8 b1 = *(const short8*)&kt[nt * 16 + ln][32 + quad * 8];
      float4v acc = {0.f,0.f,0.f,0.f};
      acc = __builtin_amdgcn_mfma_f32_16x16x32_bf16(qf[0], b0, acc, 0, 0, 0);
      acc = __builtin_amdgcn_mfma_f32_16x16x32_bf16(qf[1], b1, acc, 0, 0, 0);
      s[nt] = acc;
    }
    if (j == qt) {
      #pragma unroll
      for (int nt = 0; nt < 4; ++nt) {
        const int col = nt * 16 + ln;
        #pragma unroll
        for (int rg = 0; rg < 4; ++rg)
          if (col > wave * 16 + quad * 4 + rg) s[nt][rg] = -1e30f;
      }
    }
    #pragma unroll
    for (int rg = 0; rg < 4; ++rg) {
      float p0 = __builtin_amdgcn_exp2f(s[0][rg]);
      float p1 = __builtin_amdgcn_exp2f(s[1][rg]);
      float p2 = __builtin_amdgcn_exp2f(s[2][rg]);
      float p3 = __builtin_amdgcn_exp2f(s[3][rg]);
      s[0][rg]=p0; s[1][rg]=p1; s[2][rg]=p2; s[3][rg]=p3;
      float rs = (p0 + p1) + (p2 + p3);
      rs += __shfl_xor(rs, 1, 64); rs += __shfl_xor(rs, 2, 64);
      rs += __shfl_xor(rs, 4, 64); rs += __shfl_xor(rs, 8, 64);
      l_i[rg] += rs;
    }
    #pragma unroll
    for (int nt = 0; nt < 4; ++nt)
      #pragma unroll
      for (int rg = 0; rg < 4; ++rg)
        pt[wave][quad * 4 + rg][nt * 16 + ln] = __float2bfloat16(s[nt][rg]);
    short8 pa0 = *(const short8*)&pt[wave][ln][quad * 8];
    short8 pa1 = *(const short8*)&pt[wave][ln][32 + quad * 8];
    #pragma unroll
    for (int dt = 0; dt < 4; ++dt) {
      short8 vb0 = *(const short8*)&vt[dt * 16 + ln][quad * 8];
      short8 vb1 = *(const short8*)&vt[dt * 16 + ln][32 + quad * 8];
      o[dt] = __builtin_amdgcn_mfma_f32_16x16x32_bf16(pa0, vb0, o[dt], 0, 0, 0);
      o[dt] = __builtin_amdgcn_mfma_f32_16x16x32_bf16(pa1, vb1, o[dt], 0, 0, 0);
    }
  }
  #pragma unroll
  for (int rg = 0; rg < 4; ++rg) {
    const float inv = 1.0f / l_i[rg];
    const int row = q0 + wave * 16 + quad * 4 + rg;
    float* op = Og + base + (size_t)row * DIM + ln;
    #pragma unroll
    for (int dt = 0; dt < 4; ++dt) op[dt * 16] = o[dt][rg] * inv;
  }
}

extern "C" void kernel_launch(void* const* d_in, const int* in_sizes, int n_in,
                              void* d_out, int out_size, void* d_ws, size_t ws_size,
                              hipStream_t stream) {
  (void)in_sizes; (void)n_in; (void)out_size;
  const float* Q = (const float*)d_in[0];
  const float* K = (const float*)d_in[1];
  const float* V = (const float*)d_in[2];
  float* O = (float*)d_out;
  const size_t need = (size_t)2 * BHN * SEQ * DIM * sizeof(__hip_bfloat16); // 16 MB
  if (ws_size >= need) {
    __hip_bfloat16* Kb = (__hip_bfloat16*)d_ws;
    __hip_bfloat16* Vt = Kb + (size_t)BHN * SEQ * DIM;
    prep_kernel<<<dim3(BHN, SEQ / 64), 256, 0, stream>>>(K, V, Kb, Vt);
    fattn11<<<dim3(BHN, 32), 128, 0, stream>>>(Q, Kb, Vt, O);
  } else {
    fattn_ref<<<dim3(BHN, SEQ / 64), 256, 0, stream>>>(Q, K, V, O);
  }
}